// Round 14
// baseline (723.282 us; speedup 1.0000x reference)
//
#include <hip/hip_runtime.h>
#include <math.h>

#define H 64
#define VOCABN 64
#define LSEQ 2048
#define LN_EPS 1e-5f

// ---------- generic DPP add helper ----------
template <int CTRL>
__device__ __forceinline__ float dpp_add(float x) {
  return x + __int_as_float(__builtin_amdgcn_update_dpp(
      0, __float_as_int(x), CTRL, 0xF, 0xF, true));
}

// all-lane sum with broadcast result (tables / readout only)
__device__ __forceinline__ float wave_allsum(float x) {
  x = dpp_add<0xB1>(x);   // quad_perm [1,0,3,2]
  x = dpp_add<0x4E>(x);   // quad_perm [2,3,0,1]
  x = dpp_add<0x141>(x);  // row_half_mirror
  x = dpp_add<0x140>(x);  // row_mirror
  x += __shfl_xor(x, 16, 64);
  x += __shfl_xor(x, 32, 64);
  return x;
}

// all-VALU wave64 reduction: lane 63 holds the total (rounds 3/7-13 validated)
__device__ __forceinline__ float reduce_to_lane63(float x) {
  x = dpp_add<0x111>(x);  // row_shr:1
  x = dpp_add<0x112>(x);  // row_shr:2
  x = dpp_add<0x114>(x);  // row_shr:4
  x = dpp_add<0x118>(x);  // row_shr:8
  x = dpp_add<0x142>(x);  // row_bcast:15
  x = dpp_add<0x143>(x);  // row_bcast:31
  return x;
}

// norm (sqrt of wave-total of x*x), uniform via readlane 63
__device__ __forceinline__ float wave_norm63(float x) {
  float nd2 = reduce_to_lane63(x * x);
  return sqrtf(__int_as_float(__builtin_amdgcn_readlane(__float_as_int(nd2), 63)));
}

// ---------------- Kernel A: per-token tables (verbatim rounds 7-13, passed) ----------------
__global__ __launch_bounds__(64) void tables_kernel(
    const float* __restrict__ embed, const float* __restrict__ W1, const float* __restrict__ b1,
    const float* __restrict__ W2, const float* __restrict__ b2,
    const float* __restrict__ ln_g, const float* __restrict__ ln_b,
    const float* __restrict__ Wk, const float* __restrict__ Wv,
    float* __restrict__ Htab, float* __restrict__ Ktab, float* __restrict__ Vtab,
    float* __restrict__ nvtab)
{
  __shared__ float hs[H];
  __shared__ float ff1[2 * H];
  __shared__ float lns[H];
  const int c = blockIdx.x;
  const int i = threadIdx.x;

  float e = embed[c * H + i];
  hs[i] = e;
  __syncthreads();

  float r1 = b1[i], r2 = b1[i + H];
  for (int j = 0; j < H; ++j) {
    float hj = hs[j];
    r1 = fmaf(W1[i * H + j], hj, r1);
    r2 = fmaf(W1[(i + H) * H + j], hj, r2);
  }
  ff1[i]     = fmaxf(r1, 0.f);
  ff1[i + H] = fmaxf(r2, 0.f);
  __syncthreads();

  float o = b2[i];
  for (int m = 0; m < 2 * H; ++m) o = fmaf(W2[i * 2 * H + m], ff1[m], o);
  float y = e + o;

  float mu  = wave_allsum(y) * (1.f / H);
  float d   = y - mu;
  float var = wave_allsum(d * d) * (1.f / H);
  float ln  = d * (1.f / sqrtf(var + LN_EPS)) * ln_g[i] + ln_b[i];
  lns[i] = ln;
  __syncthreads();
  Htab[c * H + i] = ln;

  float k = 0.f, v = 0.f;
  for (int j = 0; j < H; ++j) {
    float lj = lns[j];
    k = fmaf(Wk[i * H + j], lj, k);
    v = fmaf(Wv[i * H + j], lj, v);
  }
  float nk = sqrtf(wave_allsum(k * k));
  Ktab[c * H + i] = k / fmaxf(nk, 1e-12f);
  Vtab[c * H + i] = v;
  float nv = sqrtf(wave_allsum(v * v));
  if (i == 0) nvtab[c] = 0.4f * nv;   // gate threshold, sqrt domain
}

// ---------------- Kernel B: double-buffered eager scan, speculative gate ----------------
// One block (4 waves) per batch element. R double-buffered in LDS: accept RMW reads
// cur, writes nxt (all 64 rows) -> no read-fence barrier; ONE barrier per accept.
// Reject-path next-gate (DPP chain on in-register rvn) is computed speculatively
// BEFORE this step's gate resolves; accept-path recompute overlaps RMW + barrier.
// All gate values/deltas bitwise identical to rounds 10-13.
__global__ __launch_bounds__(256, 1) void scan_kernel(
    const int* __restrict__ x, const float* __restrict__ Htab,
    const float* __restrict__ Ktab, const float* __restrict__ Vtab,
    const float* __restrict__ nvtab,
    const float* __restrict__ Wq, const float* __restrict__ Wr,
    const float* __restrict__ alpha, const float* __restrict__ Wout,
    const float* __restrict__ bout, float* __restrict__ out)
{
  __shared__ float4 Kl4[VOCABN * H / 4];   // khat [c][j]; becomes M_N after scan
  __shared__ float4 Vl4[VOCABN * H / 4];   // v [c][i];   becomes M_T after scan
  __shared__ float4 Gl4[VOCABN * H / 4];   // Gram [c][cc] (static after init)
  __shared__ float4 Ra4[VOCABN * H / 4];   // residual buffer A
  __shared__ float4 Rb4[VOCABN * H / 4];   // residual buffer B
  __shared__ int4   xl4[LSEQ / 4];
  __shared__ float  thl[VOCABN];           // 0.4*||v||
  __shared__ float  hbuf[H];
  __shared__ float  qbuf[H];
  __shared__ float  mbuf[H];
  float* Kl = (float*)Kl4;
  float* Vl = (float*)Vl4;
  float* Gl = (float*)Gl4;
  int*   xl = (int*)xl4;

  const int b    = blockIdx.x;
  const int tid  = threadIdx.x;
  const int lane = tid & 63;
  const int wid  = tid >> 6;

  // ---- stage tables + token row into LDS (256 threads) ----
  {
    const float4* Kg = (const float4*)Ktab;
    const float4* Vg = (const float4*)Vtab;
    for (int q = tid; q < VOCABN * H / 4; q += 256) {
      float4 vq = Vg[q];
      Kl4[q] = Kg[q]; Vl4[q] = vq; Ra4[q] = vq;   // R(A) init = v (M = 0)
    }
    const int4* xg = (const int4*)(x + b * LSEQ);
    for (int q = tid; q < LSEQ / 4; q += 256) xl4[q] = xg[q];
    if (tid < VOCABN) thl[tid] = nvtab[tid];
  }
  __syncthreads();

  // ---- Gram in LDS, rows split across waves (verbatim rounds 10-13) ----
  {
    float4 kr[16];
#pragma unroll
    for (int q = 0; q < 16; ++q) kr[q] = Kl4[lane * 16 + q];
    for (int r = 0; r < 16; ++r) {
      const int c2 = wid * 16 + r;
      const float4* kp2 = (const float4*)(Kl + c2 * H);
      float a0 = 0.f, a1 = 0.f, a2 = 0.f, a3 = 0.f;
#pragma unroll
      for (int q = 0; q < 16; ++q) {
        float4 kq = kp2[q];
        a0 = fmaf(kr[q].x, kq.x, a0);
        a1 = fmaf(kr[q].y, kq.y, a1);
        a2 = fmaf(kr[q].z, kq.z, a2);
        a3 = fmaf(kr[q].w, kq.w, a3);
      }
      Gl[c2 * H + lane] = (a0 + a1) + (a2 + a3);
    }
  }
  __syncthreads();

  // M column slice: Mw[q] holds M[lane][wid*16 + 4q .. 4q+3]
  float4 Mw[4];
#pragma unroll
  for (int q = 0; q < 4; ++q) Mw[q] = make_float4(0.f, 0.f, 0.f, 0.f);

  float* cur = (float*)Ra4;
  float* nxt = (float*)Rb4;

  // pipeline state (invariant at top of step t: rv = state[c0], rvn = state[c1],
  // nds0 = ||rv|| precomputed)
  int   c0 = xl[0], c1 = xl[1];
  float rv   = cur[c0 * H + lane];
  float rvn  = cur[c1 * H + lane];
  float th0  = thl[c0], th1 = thl[c1];
  float nds0 = wave_norm63(rv);

  for (int t = 0; t < LSEQ; ++t) {
    const int ix2 = (t + 2 < LSEQ) ? t + 2 : LSEQ - 1;
    const int c2  = xl[ix2];
    float rb2  = cur[c2 * H + lane];    // reads only cur; writes only hit nxt
    float th2v = thl[c2];
    float g01  = Gl[c0 * H + c1];       // Gram static -> race-free
    float g02  = Gl[c0 * H + c2];

    // speculative next-gate (reject hypothesis): independent of this gate
    float nds_rej = wave_norm63(rvn);

    float thu = __int_as_float(__builtin_amdgcn_readfirstlane(__float_as_int(th0)));
    float nds_next;

    if (nds0 > thu) {                   // block-uniform accept
      const float delta = rv;
      // in-register forwarding (bitwise == nxt[c1], nxt[c2] written below)
      rvn = fmaf(-g01, delta, rvn);
      rb2 = fmaf(-g02, delta, rb2);
      // accept-path next-gate: DPP chain overlaps RMW issue below
      nds_next = wave_norm63(rvn);
      // G row slice as 4 broadcast b128
      const float4* gp = ((const float4*)(Gl + c0 * H)) + wid * 4;
      float4 ga = gp[0], gb = gp[1], gc = gp[2], gd = gp[3];
      float gs[16] = {ga.x, ga.y, ga.z, ga.w, gb.x, gb.y, gb.z, gb.w,
                      gc.x, gc.y, gc.z, gc.w, gd.x, gd.y, gd.z, gd.w};
      // RMW cur -> nxt, 16 rows/wave (all 64 rows rewritten)
#pragma unroll
      for (int r = 0; r < 16; ++r) {
        const int cc = wid * 16 + r;
        nxt[cc * H + lane] = fmaf(-gs[r], delta, cur[cc * H + lane]);
      }
      // M column slice (16 FMA + 4 broadcast b128)
      const float4* kp = ((const float4*)(Kl + c0 * H)) + wid * 4;
#pragma unroll
      for (int q = 0; q < 4; ++q) {
        float4 k4 = kp[q];
        Mw[q].x = fmaf(delta, k4.x, Mw[q].x);
        Mw[q].y = fmaf(delta, k4.y, Mw[q].y);
        Mw[q].z = fmaf(delta, k4.z, Mw[q].z);
        Mw[q].w = fmaf(delta, k4.w, Mw[q].w);
      }
      __syncthreads();                  // nxt complete before anyone reads it
      float* tmp = cur; cur = nxt; nxt = tmp;
    } else {
      nds_next = nds_rej;
    }

    rv = rvn; rvn = rb2; nds0 = nds_next;
    c0 = c1; c1 = c2; th0 = th1; th1 = th2v;
  }

  // ---- reassemble M into LDS: Vl = M_T (conflict-free), Kl = M_N (verbatim rounds 12/13) ----
  __syncthreads();
#pragma unroll
  for (int r = 0; r < 4; ++r) {
    const int jb = wid * 16 + r * 4;
    float4 m = Mw[r];
    Vl[(jb + 0) * H + lane] = m.x;
    Vl[(jb + 1) * H + lane] = m.y;
    Vl[(jb + 2) * H + lane] = m.z;
    Vl[(jb + 3) * H + lane] = m.w;
    Kl[lane * H + jb + 0] = m.x;
    Kl[lane * H + jb + 1] = m.y;
    Kl[lane * H + jb + 2] = m.z;
    Kl[lane * H + jb + 3] = m.w;
  }
  __syncthreads();

  // ---------------- fused readout: wave 0 (M from LDS; verbatim rounds 12/13, passed) ----------------
  if (wid == 0) {
    const int clast = xl[LSEQ - 1];
    hbuf[lane] = Htab[clast * H + lane];

    float qi = 0.f;
    for (int j = 0; j < H; ++j) qi = fmaf(Wq[lane * H + j], hbuf[j], qi);
    qbuf[lane] = qi;

    float qri = 0.f;
    for (int j = 0; j < H; ++j) qri = fmaf(Wr[lane * H + j], qbuf[j], qri);

    // slot norms^2: lane s reads M_N column s (conflict-free)
    float n2 = 0.f;
    for (int i2 = 0; i2 < H; ++i2) { float m = Kl[i2 * H + lane]; n2 = fmaf(m, m, n2); }

    // top-8 slots by norm (ties -> smaller index)
    const int KS = 8;
    int idxs[KS];
    float nloc = n2;
#pragma unroll
    for (int k = 0; k < KS; ++k) {
      float v = nloc; int idx = lane;
#pragma unroll
      for (int s = 1; s < 64; s <<= 1) {
        float ov = __shfl_xor(v, s, 64);
        int   oi = __shfl_xor(idx, s, 64);
        if (ov > v || (ov == v && oi < idx)) { v = ov; idx = oi; }
      }
      idxs[k] = idx;
      if (lane == idx) nloc = -1.f;
    }

    float sel[KS], lg[KS];
#pragma unroll
    for (int k = 0; k < KS; ++k) {
      float s = Vl[idxs[k] * H + lane];     // M_T[idx][lane]
      sel[k] = s;
      lg[k] = wave_allsum(s * qri) * 0.125f;   // / sqrt(64)
    }
    float lmax = lg[0];
#pragma unroll
    for (int k = 1; k < KS; ++k) lmax = fmaxf(lmax, lg[k]);
    float esum = 0.f, retro = 0.f;
#pragma unroll
    for (int k = 0; k < KS; ++k) {
      float e = expf(lg[k] - lmax);
      esum += e;
      retro = fmaf(e, sel[k], retro);
    }
    retro /= esum;

    // m_ctx = M q : lane i, ascending j reading M_T[j][lane] (conflict-free)
    float mc = 0.f;
    for (int j = 0; j < H; ++j) mc = fmaf(Vl[j * H + lane], qbuf[j], mc);

    float a = 1.f / (1.f + expf(-alpha[0]));
    float mixed = fmaxf(fmaf(a, retro, (1.f - a) * mc), 0.f);
    mbuf[lane] = mixed;

    float oo = bout[lane];
    for (int i2 = 0; i2 < H; ++i2) oo = fmaf(Wout[lane * H + i2], mbuf[i2], oo);
    out[b * VOCABN + lane] = oo;
  }
}

extern "C" void kernel_launch(void* const* d_in, const int* in_sizes, int n_in,
                              void* d_out, int out_size, void* d_ws, size_t ws_size,
                              hipStream_t stream) {
  const int*   x     = (const int*)d_in[0];
  const float* embed = (const float*)d_in[1];
  const float* W1    = (const float*)d_in[2];
  const float* b1    = (const float*)d_in[3];
  const float* W2    = (const float*)d_in[4];
  const float* b2    = (const float*)d_in[5];
  const float* ln_g  = (const float*)d_in[6];
  const float* ln_b  = (const float*)d_in[7];
  const float* Wk    = (const float*)d_in[8];
  const float* Wv    = (const float*)d_in[9];
  const float* Wq    = (const float*)d_in[10];
  const float* Wr    = (const float*)d_in[11];
  const float* alpha = (const float*)d_in[12];
  const float* Wout  = (const float*)d_in[13];
  const float* bout  = (const float*)d_in[14];
  float* out = (float*)d_out;

  const int B = in_sizes[0] / LSEQ;

  float* ws    = (float*)d_ws;
  float* Htab  = ws;          // 4096
  float* Ktab  = ws + 4096;   // 4096
  float* Vtab  = ws + 8192;   // 4096
  float* nvtab = ws + 12288;  // 64

  tables_kernel<<<VOCABN, 64, 0, stream>>>(embed, W1, b1, W2, b2, ln_g, ln_b,
                                           Wk, Wv, Htab, Ktab, Vtab, nvtab);
  scan_kernel<<<B, 256, 0, stream>>>(x, Htab, Ktab, Vtab, nvtab,
                                     Wq, Wr, alpha, Wout, bout, out);
}